// Round 1
// baseline (297.670 us; speedup 1.0000x reference)
//
#include <hip/hip_runtime.h>
#include <hip/hip_bf16.h>
#include <math.h>

#define NROW 8192
#define DDIM 256
#define BM 128
#define BN 128
#define BK 64
#define LDS_STRIDE (BK + 8)   // 72 elems = 144 B rows (16B-aligned, breaks 16-way bank conflict)

typedef __attribute__((ext_vector_type(8))) short bf16x8;
typedef __attribute__((ext_vector_type(4))) float f32x4;

static __device__ inline unsigned short f2bf(float x) {
    union { float f; unsigned int u; } v; v.f = x;
    unsigned int r = v.u + 0x7fffu + ((v.u >> 16) & 1u);  // RNE
    return (unsigned short)(r >> 16);
}

// One wave per row: compute L2 norms of H1[row], H2[row], write bf16 normalized
// rows, and diag[row] = 2 * dot(z1n_row, z2n_row) in fp32.
__global__ __launch_bounds__(256) void normalize_kernel(
        const float* __restrict__ h1, const float* __restrict__ h2,
        unsigned short* __restrict__ z1b, unsigned short* __restrict__ z2b,
        float* __restrict__ diag) {
    int wave = threadIdx.x >> 6;
    int lane = threadIdx.x & 63;
    int row  = blockIdx.x * 4 + wave;
    const float4* p1 = (const float4*)(h1 + (size_t)row * DDIM);
    const float4* p2 = (const float4*)(h2 + (size_t)row * DDIM);
    float4 a = p1[lane];
    float4 b = p2[lane];
    float s1 = a.x*a.x + a.y*a.y + a.z*a.z + a.w*a.w;
    float s2 = b.x*b.x + b.y*b.y + b.z*b.z + b.w*b.w;
    #pragma unroll
    for (int m = 1; m < 64; m <<= 1) { s1 += __shfl_xor(s1, m); s2 += __shfl_xor(s2, m); }
    float r1 = 1.0f / fmaxf(sqrtf(s1), 1e-12f);
    float r2 = 1.0f / fmaxf(sqrtf(s2), 1e-12f);
    float n1x = a.x*r1, n1y = a.y*r1, n1z = a.z*r1, n1w = a.w*r1;
    float n2x = b.x*r2, n2y = b.y*r2, n2z = b.z*r2, n2w = b.w*r2;
    float dt = n1x*n2x + n1y*n2y + n1z*n2z + n1w*n2w;
    #pragma unroll
    for (int m = 1; m < 64; m <<= 1) dt += __shfl_xor(dt, m);
    if (lane == 0) diag[row] = 2.0f * dt;
    ushort4 o1, o2;
    o1.x = f2bf(n1x); o1.y = f2bf(n1y); o1.z = f2bf(n1z); o1.w = f2bf(n1w);
    o2.x = f2bf(n2x); o2.y = f2bf(n2y); o2.z = f2bf(n2z); o2.w = f2bf(n2w);
    ((ushort4*)(z1b + (size_t)row * DDIM))[lane] = o1;
    ((ushort4*)(z2b + (size_t)row * DDIM))[lane] = o2;
}

// Tile (blockIdx.y, blockIdx.x) of matrix selected by blockIdx.z:
//   z=0: S11 = Z1*Z1^T -> rowsum rs1
//   z=1: S22 = Z2*Z2^T -> rowsum rs2
//   z=2: S12 = Z1*Z2^T -> rowsum rbr, colsum rbc
// Accumulates sum_j exp(2*S_ij) via MFMA + in-register exp + shuffles + atomics.
__global__ __launch_bounds__(256, 2) void expsum_kernel(
        const unsigned short* __restrict__ z1, const unsigned short* __restrict__ z2,
        float* __restrict__ rs1, float* __restrict__ rs2,
        float* __restrict__ rbr, float* __restrict__ rbc) {
    const unsigned short* Ap;
    const unsigned short* Bp;
    float* rowsum;
    float* colsum = nullptr;
    if (blockIdx.z == 0)      { Ap = z1; Bp = z1; rowsum = rs1; }
    else if (blockIdx.z == 1) { Ap = z2; Bp = z2; rowsum = rs2; }
    else                      { Ap = z1; Bp = z2; rowsum = rbr; colsum = rbc; }

    const int rt = blockIdx.y * BM;
    const int ct = blockIdx.x * BN;

    __shared__ __align__(16) unsigned short lA[BM * LDS_STRIDE];
    __shared__ __align__(16) unsigned short lB[BN * LDS_STRIDE];

    const int tid  = threadIdx.x;
    const int lane = tid & 63;
    const int wid  = tid >> 6;   // 4 waves
    const int wr   = wid >> 1;   // wave row 0..1  (64-row strip)
    const int wc   = wid & 1;    // wave col 0..1  (64-col strip)
    const int quad = lane >> 4;
    const int l15  = lane & 15;

    f32x4 acc[4][4];
    #pragma unroll
    for (int mi = 0; mi < 4; ++mi)
        #pragma unroll
        for (int ni = 0; ni < 4; ++ni)
            acc[mi][ni] = (f32x4){0.f, 0.f, 0.f, 0.f};

    for (int kt = 0; kt < DDIM; kt += BK) {
        // Stage A (128x64) and B (128x64) bf16 tiles into LDS, 16B per thread per pass.
        #pragma unroll
        for (int it = 0; it < 4; ++it) {
            int slot = it * 256 + tid;        // 0..1023
            int row  = slot >> 3;             // 0..127
            int c8   = (slot & 7) * 8;        // 0,8,...,56
            uint4 va = *((const uint4*)(Ap + (size_t)(rt + row) * DDIM + kt + c8));
            *((uint4*)(lA + row * LDS_STRIDE + c8)) = va;
            uint4 vb = *((const uint4*)(Bp + (size_t)(ct + row) * DDIM + kt + c8));
            *((uint4*)(lB + row * LDS_STRIDE + c8)) = vb;
        }
        __syncthreads();
        #pragma unroll
        for (int ks = 0; ks < 2; ++ks) {
            bf16x8 af[4], bfr[4];
            #pragma unroll
            for (int mi = 0; mi < 4; ++mi) {
                int r = wr * 64 + mi * 16 + l15;
                af[mi] = *((const bf16x8*)(lA + r * LDS_STRIDE + ks * 32 + quad * 8));
            }
            #pragma unroll
            for (int ni = 0; ni < 4; ++ni) {
                int c = wc * 64 + ni * 16 + l15;
                bfr[ni] = *((const bf16x8*)(lB + c * LDS_STRIDE + ks * 32 + quad * 8));
            }
            #pragma unroll
            for (int mi = 0; mi < 4; ++mi)
                #pragma unroll
                for (int ni = 0; ni < 4; ++ni)
                    acc[mi][ni] = __builtin_amdgcn_mfma_f32_16x16x32_bf16(
                        af[mi], bfr[ni], acc[mi][ni], 0, 0, 0);
        }
        __syncthreads();
    }

    // C/D layout (m89-verified): col = lane&15, row = (lane>>4)*4 + reg.
    float colpart[4] = {0.f, 0.f, 0.f, 0.f};
    #pragma unroll
    for (int mi = 0; mi < 4; ++mi) {
        #pragma unroll
        for (int r = 0; r < 4; ++r) {
            float rp = 0.f;
            #pragma unroll
            for (int ni = 0; ni < 4; ++ni) {
                float e = __expf(2.0f * acc[mi][ni][r]);
                rp += e;
                colpart[ni] += e;
            }
            rp += __shfl_xor(rp, 1);
            rp += __shfl_xor(rp, 2);
            rp += __shfl_xor(rp, 4);
            rp += __shfl_xor(rp, 8);
            if (l15 == 0) {
                int grow = rt + wr * 64 + mi * 16 + quad * 4 + r;
                atomicAdd(&rowsum[grow], rp);
            }
        }
    }
    if (colsum) {
        #pragma unroll
        for (int ni = 0; ni < 4; ++ni) {
            float cp = colpart[ni];
            cp += __shfl_xor(cp, 16);
            cp += __shfl_xor(cp, 32);
            if (lane < 16) {
                int gcol = ct + wc * 64 + ni * 16 + l15;
                atomicAdd(&colsum[gcol], cp);
            }
        }
    }
}

__global__ __launch_bounds__(1024) void finalize_kernel(
        const float* __restrict__ rs1, const float* __restrict__ rs2,
        const float* __restrict__ rbr, const float* __restrict__ rbc,
        const float* __restrict__ diag, float* __restrict__ out) {
    __shared__ float sdata[16];
    const float E2 = 7.38905609893065f;   // exp(1/tau), tau=0.5
    float acc = 0.f;
    for (int i = threadIdx.x; i < NROW; i += blockDim.x) {
        float den1 = rs1[i] + rbr[i] - E2;
        float den2 = rs2[i] + rbc[i] - E2;
        acc += 0.5f * (logf(den1) + logf(den2)) - diag[i];
    }
    #pragma unroll
    for (int m = 1; m < 64; m <<= 1) acc += __shfl_xor(acc, m);
    if ((threadIdx.x & 63) == 0) sdata[threadIdx.x >> 6] = acc;
    __syncthreads();
    if (threadIdx.x < 16) {
        float v = sdata[threadIdx.x];
        #pragma unroll
        for (int m = 1; m < 16; m <<= 1) v += __shfl_xor(v, m);
        if (threadIdx.x == 0) out[0] = v / (float)NROW;
    }
}

extern "C" void kernel_launch(void* const* d_in, const int* in_sizes, int n_in,
                              void* d_out, int out_size, void* d_ws, size_t ws_size,
                              hipStream_t stream) {
    const float* h1 = (const float*)d_in[0];
    const float* h2 = (const float*)d_in[1];
    float* out = (float*)d_out;

    char* ws = (char*)d_ws;
    unsigned short* z1b = (unsigned short*)ws;                                // 4 MB
    unsigned short* z2b = (unsigned short*)(ws + (size_t)NROW * DDIM * 2);    // 4 MB
    float* sums = (float*)(ws + (size_t)2 * NROW * DDIM * 2);
    float* rs1  = sums;
    float* rs2  = sums + NROW;
    float* rbr  = sums + 2 * NROW;
    float* rbc  = sums + 3 * NROW;
    float* diag = sums + 4 * NROW;

    hipMemsetAsync(sums, 0, (size_t)4 * NROW * sizeof(float), stream);

    normalize_kernel<<<NROW / 4, 256, 0, stream>>>(h1, h2, z1b, z2b, diag);

    dim3 grid(NROW / BN, NROW / BM, 3);
    expsum_kernel<<<grid, 256, 0, stream>>>(z1b, z2b, rs1, rs2, rbr, rbc);

    finalize_kernel<<<1, 1024, 0, stream>>>(rs1, rs2, rbr, rbc, diag, out);
}

// Round 2
// 191.111 us; speedup vs baseline: 1.5576x; 1.5576x over previous
//
#include <hip/hip_runtime.h>
#include <hip/hip_bf16.h>
#include <math.h>

#define NROW 8192
#define DDIM 256
#define BM 128
#define BN 128
#define BK 64
#define NT_SYM 2080    // 64*65/2 lower-triangular 128x128 tiles
#define NT_FULL 4096

typedef __attribute__((ext_vector_type(8))) short bf16x8;
typedef __attribute__((ext_vector_type(4))) float f32x4;
typedef __attribute__((address_space(3))) unsigned int lds_u32;
typedef const __attribute__((address_space(1))) unsigned int glb_u32;

static __device__ inline unsigned short f2bf(float x) {
    union { float f; unsigned int u; } v; v.f = x;
    unsigned int r = v.u + 0x7fffu + ((v.u >> 16) & 1u);  // RNE
    return (unsigned short)(r >> 16);
}

// One wave per row: L2-normalize H1/H2 rows, scale by sqrt(2) (so bf16 dot
// products carry the 2/tau factor), write bf16; diag[row] = 2*dot(z1n,z2n) fp32.
// Also zero-inits the 4 rowsum accumulators (replaces a memset dispatch).
__global__ __launch_bounds__(256) void normalize_kernel(
        const float* __restrict__ h1, const float* __restrict__ h2,
        unsigned short* __restrict__ z1b, unsigned short* __restrict__ z2b,
        float* __restrict__ diag,
        float* __restrict__ rs1, float* __restrict__ rs2,
        float* __restrict__ rbr, float* __restrict__ rbc) {
    int wave = threadIdx.x >> 6;
    int lane = threadIdx.x & 63;
    int row  = blockIdx.x * 4 + wave;
    const float4* p1 = (const float4*)(h1 + (size_t)row * DDIM);
    const float4* p2 = (const float4*)(h2 + (size_t)row * DDIM);
    float4 a = p1[lane];
    float4 b = p2[lane];
    float s1 = a.x*a.x + a.y*a.y + a.z*a.z + a.w*a.w;
    float s2 = b.x*b.x + b.y*b.y + b.z*b.z + b.w*b.w;
    #pragma unroll
    for (int m = 1; m < 64; m <<= 1) { s1 += __shfl_xor(s1, m); s2 += __shfl_xor(s2, m); }
    float r1 = 1.0f / fmaxf(sqrtf(s1), 1e-12f);
    float r2 = 1.0f / fmaxf(sqrtf(s2), 1e-12f);
    float n1x = a.x*r1, n1y = a.y*r1, n1z = a.z*r1, n1w = a.w*r1;
    float n2x = b.x*r2, n2y = b.y*r2, n2z = b.z*r2, n2w = b.w*r2;
    float dt = n1x*n2x + n1y*n2y + n1z*n2z + n1w*n2w;
    #pragma unroll
    for (int m = 1; m < 64; m <<= 1) dt += __shfl_xor(dt, m);
    if (lane == 0) {
        diag[row] = 2.0f * dt;
        rs1[row] = 0.f; rs2[row] = 0.f; rbr[row] = 0.f; rbc[row] = 0.f;
    }
    const float SQ2 = 1.41421356237309515f;
    ushort4 o1, o2;
    o1.x = f2bf(n1x*SQ2); o1.y = f2bf(n1y*SQ2); o1.z = f2bf(n1z*SQ2); o1.w = f2bf(n1w*SQ2);
    o2.x = f2bf(n2x*SQ2); o2.y = f2bf(n2y*SQ2); o2.z = f2bf(n2z*SQ2); o2.w = f2bf(n2w*SQ2);
    ((ushort4*)(z1b + (size_t)row * DDIM))[lane] = o1;
    ((ushort4*)(z2b + (size_t)row * DDIM))[lane] = o2;
}

// Tiles: b < 2080 -> S11 lower-tri tile; < 4160 -> S22 lower-tri; else S12 full.
// Symmetric matrices: off-diagonal tile adds rowpart to rowsum[rows] AND
// colpart to rowsum[cols] (same array). Staging via global_load_lds width=16
// into an unpadded 128B-row LDS tile with XOR chunk swizzle (slot = chunk^(row&7))
// applied on the global-address side -> conflict-free ds_read_b128 fragments.
__global__ __launch_bounds__(256, 4) void expsum_kernel(
        const unsigned short* __restrict__ z1, const unsigned short* __restrict__ z2,
        float* __restrict__ rs1, float* __restrict__ rs2,
        float* __restrict__ rbr, float* __restrict__ rbc) {
    int b = blockIdx.x;
    int kind, t;
    if (b < NT_SYM)            { kind = 0; t = b; }
    else if (b < 2 * NT_SYM)   { kind = 1; t = b - NT_SYM; }
    else                       { kind = 2; t = b - 2 * NT_SYM; }

    int by, bx;
    const unsigned short *Ap, *Bp;
    float *rowsum, *colsum;
    if (kind == 2) {
        by = t >> 6; bx = t & 63;
        Ap = z1; Bp = z2; rowsum = rbr; colsum = rbc;
    } else {
        by = (int)((sqrtf(8.0f * (float)t + 1.0f) - 1.0f) * 0.5f);
        while ((by + 1) * (by + 2) / 2 <= t) ++by;
        while (by * (by + 1) / 2 > t) --by;
        bx = t - by * (by + 1) / 2;          // bx <= by (lower triangular)
        const unsigned short* z = (kind == 0) ? z1 : z2;
        Ap = z; Bp = z;
        rowsum = (kind == 0) ? rs1 : rs2;
        colsum = (bx == by) ? nullptr : rowsum;
    }

    const int rt = by * BM;
    const int ct = bx * BN;

    __shared__ __align__(16) unsigned short lA[BM * BK];  // 16 KB, rows of 128 B
    __shared__ __align__(16) unsigned short lB[BN * BK];  // 16 KB

    const int tid  = threadIdx.x;
    const int lane = tid & 63;
    const int wid  = tid >> 6;
    const int wr   = wid >> 1;
    const int wc   = wid & 1;
    const int quad = lane >> 4;
    const int l15  = lane & 15;

    // Per-lane staging offsets: lane i covers row i>>3, LDS slot i&7 of an
    // 8-row group; swizzle: that slot must hold global chunk (i&7)^(i>>3).
    const int srow  = lane >> 3;
    const int schunk = (lane & 7) ^ srow;          // global chunk to fetch
    const int gcol0  = schunk * 8;                 // element offset in row

    f32x4 acc[4][4];
    #pragma unroll
    for (int mi = 0; mi < 4; ++mi)
        #pragma unroll
        for (int ni = 0; ni < 4; ++ni)
            acc[mi][ni] = (f32x4){0.f, 0.f, 0.f, 0.f};

    for (int kt = 0; kt < DDIM; kt += BK) {
        // Stage A and B 128x64 tiles: 4 waves x 4 groups x 8 rows, 16 B/lane DMA.
        #pragma unroll
        for (int p = 0; p < 4; ++p) {
            int g  = p * 4 + wid;      // row-group 0..15
            int r0 = g * 8;
            const unsigned short* ga = Ap + (size_t)(rt + r0 + srow) * DDIM + kt + gcol0;
            __builtin_amdgcn_global_load_lds((glb_u32*)ga, (lds_u32*)(lA + r0 * BK), 16, 0, 0);
            const unsigned short* gb = Bp + (size_t)(ct + r0 + srow) * DDIM + kt + gcol0;
            __builtin_amdgcn_global_load_lds((glb_u32*)gb, (lds_u32*)(lB + r0 * BK), 16, 0, 0);
        }
        __syncthreads();
        #pragma unroll
        for (int ks = 0; ks < 2; ++ks) {
            bf16x8 af[4], bfr[4];
            #pragma unroll
            for (int mi = 0; mi < 4; ++mi) {
                int r = wr * 64 + mi * 16 + l15;
                int slot = (ks * 4 + quad) ^ (l15 & 7);
                af[mi] = *((const bf16x8*)(lA + r * BK + slot * 8));
            }
            #pragma unroll
            for (int ni = 0; ni < 4; ++ni) {
                int c = wc * 64 + ni * 16 + l15;
                int slot = (ks * 4 + quad) ^ (l15 & 7);
                bfr[ni] = *((const bf16x8*)(lB + c * BK + slot * 8));
            }
            #pragma unroll
            for (int mi = 0; mi < 4; ++mi)
                #pragma unroll
                for (int ni = 0; ni < 4; ++ni)
                    acc[mi][ni] = __builtin_amdgcn_mfma_f32_16x16x32_bf16(
                        af[mi], bfr[ni], acc[mi][ni], 0, 0, 0);
        }
        __syncthreads();
    }

    // C/D layout: col = lane&15, row = quad*4 + reg. acc already holds 2*S/2... = 2*s,
    // exp(2s) == __expf(acc) since the sqrt(2) scale folded the factor 2 in.
    float colpart[4] = {0.f, 0.f, 0.f, 0.f};
    #pragma unroll
    for (int mi = 0; mi < 4; ++mi) {
        #pragma unroll
        for (int r = 0; r < 4; ++r) {
            float rp = 0.f;
            #pragma unroll
            for (int ni = 0; ni < 4; ++ni) {
                float e = __expf(acc[mi][ni][r]);
                rp += e;
                colpart[ni] += e;
            }
            rp += __shfl_xor(rp, 1);
            rp += __shfl_xor(rp, 2);
            rp += __shfl_xor(rp, 4);
            rp += __shfl_xor(rp, 8);
            if (l15 == 0) {
                int grow = rt + wr * 64 + mi * 16 + quad * 4 + r;
                atomicAdd(&rowsum[grow], rp);
            }
        }
    }
    if (colsum) {
        #pragma unroll
        for (int ni = 0; ni < 4; ++ni) {
            float cp = colpart[ni];
            cp += __shfl_xor(cp, 16);
            cp += __shfl_xor(cp, 32);
            if (lane < 16) {
                int gcol = ct + wc * 64 + ni * 16 + l15;
                atomicAdd(&colsum[gcol], cp);
            }
        }
    }
}

__global__ __launch_bounds__(1024) void finalize_kernel(
        const float* __restrict__ rs1, const float* __restrict__ rs2,
        const float* __restrict__ rbr, const float* __restrict__ rbc,
        const float* __restrict__ diag, float* __restrict__ out) {
    __shared__ float sdata[16];
    const float E2 = 7.38905609893065f;   // exp(1/tau), tau=0.5
    float acc = 0.f;
    for (int i = threadIdx.x; i < NROW; i += blockDim.x) {
        float den1 = rs1[i] + rbr[i] - E2;
        float den2 = rs2[i] + rbc[i] - E2;
        acc += 0.5f * (logf(den1) + logf(den2)) - diag[i];
    }
    #pragma unroll
    for (int m = 1; m < 64; m <<= 1) acc += __shfl_xor(acc, m);
    if ((threadIdx.x & 63) == 0) sdata[threadIdx.x >> 6] = acc;
    __syncthreads();
    if (threadIdx.x < 16) {
        float v = sdata[threadIdx.x];
        #pragma unroll
        for (int m = 1; m < 16; m <<= 1) v += __shfl_xor(v, m);
        if (threadIdx.x == 0) out[0] = v / (float)NROW;
    }
}

extern "C" void kernel_launch(void* const* d_in, const int* in_sizes, int n_in,
                              void* d_out, int out_size, void* d_ws, size_t ws_size,
                              hipStream_t stream) {
    const float* h1 = (const float*)d_in[0];
    const float* h2 = (const float*)d_in[1];
    float* out = (float*)d_out;

    char* ws = (char*)d_ws;
    unsigned short* z1b = (unsigned short*)ws;                                // 4 MB
    unsigned short* z2b = (unsigned short*)(ws + (size_t)NROW * DDIM * 2);    // 4 MB
    float* sums = (float*)(ws + (size_t)2 * NROW * DDIM * 2);
    float* rs1  = sums;
    float* rs2  = sums + NROW;
    float* rbr  = sums + 2 * NROW;
    float* rbc  = sums + 3 * NROW;
    float* diag = sums + 4 * NROW;

    normalize_kernel<<<NROW / 4, 256, 0, stream>>>(h1, h2, z1b, z2b, diag,
                                                   rs1, rs2, rbr, rbc);

    expsum_kernel<<<2 * NT_SYM + NT_FULL, 256, 0, stream>>>(z1b, z2b, rs1, rs2, rbr, rbc);

    finalize_kernel<<<1, 1024, 0, stream>>>(rs1, rs2, rbr, rbc, diag, out);
}